// Round 11
// baseline (169.137 us; speedup 1.0000x reference)
//
#include <hip/hip_runtime.h>
#include <math.h>

#define B_     4
#define N_     2048
#define F_     256
#define H_     4
#define DH     64
#define BN     8192
#define SP     72    // padded f16 stride (64 + 8) -> 144 B
#define SPO2   264   // padded f16 stride for proj epilogue rows (256 + 8)
#define SPW    264   // padded f16 stride for out-kernel ctx rows

#define QSCALE 0.18033688011112042f   // 0.125 * log2(e)
#define CLIP   14.426950408889634f    // 10 * log2(e)

typedef _Float16 f16;
typedef _Float16 half8  __attribute__((ext_vector_type(8)));
typedef _Float16 half4v __attribute__((ext_vector_type(4)));
typedef float    floatx4 __attribute__((ext_vector_type(4)));
typedef unsigned long long u64;

__device__ __forceinline__ half8 cvt8(float4 a, float4 b) {
    half8 h;
    h[0] = (f16)a.x; h[1] = (f16)a.y; h[2] = (f16)a.z; h[3] = (f16)a.w;
    h[4] = (f16)b.x; h[5] = (f16)b.y; h[6] = (f16)b.z; h[7] = (f16)b.w;
    return h;
}

// ---------------------------------------------------------------------------
// Kernel 1: fused QKV projection (+ pack_adj + Wo-convert as extra blocks).
// blocks [0,384): proj; [384,416): Wo cvt; [416,8608): adj bit-pack.
// ---------------------------------------------------------------------------
__global__ __launch_bounds__(512) void proj_fused(
    const float* __restrict__ x,
    const float* __restrict__ Wq, const float* __restrict__ Wk, const float* __restrict__ Wv,
    const float* __restrict__ bq, const float* __restrict__ bk, const float* __restrict__ bv,
    const int* __restrict__ adj, u64* __restrict__ Padj,
    const float* __restrict__ Wo, f16* __restrict__ Woh,
    f16* __restrict__ Qh, f16* __restrict__ Kh, f16* __restrict__ Vt)
{
    const int bid = blockIdx.x;
    const int tid = threadIdx.x;

    if (bid >= 416) {            // ---- adj pack: 8192 blocks, 512 keys each
        const int idx = bid - 416;
        const int row = idx >> 2, seg = idx & 3;
        const int wave = tid >> 6, lane = tid & 63;
        const int key = seg * 512 + wave * 64 + lane;
        u64 m = __ballot(adj[(size_t)row * N_ + key] != 0);
        if (lane == 0) Padj[(size_t)row * 32 + seg * 8 + wave] = m;
        return;
    }
    if (bid >= 384) {            // ---- Wo fp32 -> f16: 32 blocks x 2048 elems
        const int idx = (bid - 384) * 2048 + tid * 4;
        float4 v = *(const float4*)(Wo + idx);
        half4v h; h[0] = (f16)v.x; h[1] = (f16)v.y; h[2] = (f16)v.z; h[3] = (f16)v.w;
        *(half4v*)(Woh + idx) = h;
        return;
    }

    // ---- projection: 64n x 256o tile, 512 thr, wave = 16n x 128o ----
    const int which = bid >> 7;          // 0,1,2
    const float* W    = which == 0 ? Wq : which == 1 ? Wk : Wv;
    const float* bias = which == 0 ? bq : which == 1 ? bk : bv;

    const int r0 = (bid & 127) * 64;
    const int wave = tid >> 6, lane = tid & 63;
    const int quad = lane >> 4, l16 = lane & 15;
    const int rw = wave & 3, cw = wave >> 2;       // row-group, col-group

    __shared__ f16 smem[(64 + 256) * SP];
    f16* xs = smem;
    f16* wt = smem + 64 * SP;

    floatx4 zz = {0.f, 0.f, 0.f, 0.f};
    floatx4 acc[8] = {zz, zz, zz, zz, zz, zz, zz, zz};

    const int xrow = tid >> 3, xseg = (tid & 7) * 8;   // x: 64 rows x 64 f16
    const int wrow = tid >> 1, wh = (tid & 1) * 32;    // W: 256 rows x 64 f16

    for (int f0 = 0; f0 < F_; f0 += 64) {
        const float* xsrc = x + (size_t)(r0 + xrow) * F_ + f0 + xseg;
        const float* wsrc = W + (size_t)wrow * F_ + f0 + wh;
        float4 xa0 = *(const float4*)(xsrc), xa1 = *(const float4*)(xsrc + 4);
        float4 w0 = *(const float4*)(wsrc),      w1 = *(const float4*)(wsrc + 4);
        float4 w2 = *(const float4*)(wsrc + 8),  w3 = *(const float4*)(wsrc + 12);
        float4 w4 = *(const float4*)(wsrc + 16), w5 = *(const float4*)(wsrc + 20);
        float4 w6 = *(const float4*)(wsrc + 24), w7 = *(const float4*)(wsrc + 28);
        __syncthreads();
        *(half8*)&xs[xrow * SP + xseg]     = cvt8(xa0, xa1);
        *(half8*)&wt[wrow * SP + wh]       = cvt8(w0, w1);
        *(half8*)&wt[wrow * SP + wh + 8]   = cvt8(w2, w3);
        *(half8*)&wt[wrow * SP + wh + 16]  = cvt8(w4, w5);
        *(half8*)&wt[wrow * SP + wh + 24]  = cvt8(w6, w7);
        __syncthreads();
        half8 a0 = *(const half8*)&xs[(rw * 16 + l16) * SP + quad * 8];
        half8 a1 = *(const half8*)&xs[(rw * 16 + l16) * SP + 32 + quad * 8];
#pragma unroll
        for (int ot = 0; ot < 8; ot++) {
            const int o = cw * 128 + ot * 16 + l16;
            half8 b0 = *(const half8*)&wt[o * SP + quad * 8];
            half8 b1 = *(const half8*)&wt[o * SP + 32 + quad * 8];
            acc[ot] = __builtin_amdgcn_mfma_f32_16x16x32_f16(a0, b0, acc[ot], 0, 0, 0);
            acc[ot] = __builtin_amdgcn_mfma_f32_16x16x32_f16(a1, b1, acc[ot], 0, 0, 0);
        }
    }

    const int bb = r0 >> 11, nn0 = r0 & (N_ - 1);

    if (which == 2) {
#pragma unroll
        for (int ot = 0; ot < 8; ot++) {
            const int o  = cw * 128 + ot * 16 + l16;
            const int hy = o >> 6, dh = o & 63;
            const float bv_ = bias[o];
            half4v h4;
#pragma unroll
            for (int r = 0; r < 4; r++) h4[r] = (f16)(acc[ot][r] + bv_);
            *(half4v*)(Vt + (((size_t)bb * H_ + hy) * DH + dh) * N_
                          + nn0 + rw * 16 + quad * 4) = h4;
        }
    } else {
        const float scl = (which == 0) ? QSCALE : 1.0f;
        f16* dst = which == 0 ? Qh : Kh;
        __syncthreads();
        f16* outb = smem;   // 64 x SPO2
#pragma unroll
        for (int ot = 0; ot < 8; ot++) {
            const int o = cw * 128 + ot * 16 + l16;
            const float bv_ = bias[o];
#pragma unroll
            for (int r = 0; r < 4; r++)
                outb[(rw * 16 + quad * 4 + r) * SPO2 + o] =
                    (f16)((acc[ot][r] + bv_) * scl);
        }
        __syncthreads();
        const int grow = tid >> 3, gseg = tid & 7;
        const int hh = gseg >> 1, dcol = (gseg & 1) * 32;
        f16* g = dst + (((size_t)bb * H_ + hh) * N_ + nn0 + grow) * DH + dcol;
        const f16* s = &outb[grow * SPO2 + gseg * 32];
#pragma unroll
        for (int k = 0; k < 4; k++)
            *(float4*)(g + k * 8) = *(const float4*)(s + k * 8);
    }
}

// ---------------------------------------------------------------------------
// Kernel 2: MFMA chunked attention — 256 thr (4 waves), 32 q per wave,
// 128 q per block, TWO chunks per block (split x4).  Cross-chunk totals are
// accumulated in PACKED f16 (same numerics as the out-kernel partial sum)
// so VGPR stays low (R9's fp32 totals cost +32 VGPR and killed occupancy).
// ---------------------------------------------------------------------------
__global__ __launch_bounds__(256) void attn_mfma(
    const f16* __restrict__ Qh, const f16* __restrict__ Kh,
    const f16* __restrict__ Vt, const u64* __restrict__ Padj,
    f16* __restrict__ CTXP)
{
    const int nt = blockIdx.x & 15;
    const int sp = blockIdx.x >> 4;        // split 0..3, chunks sp*2, sp*2+1
    const int qb = nt * 128;
    const int h  = blockIdx.y;
    const int b  = blockIdx.z;
    const int bh = b * H_ + h;
    const int tid  = threadIdx.x;
    const int wave = tid >> 6, lane = tid & 63;
    const int quad = lane >> 4, l16 = lane & 15;

    __shared__ f16 QPs[128 * SP];  // Q stage, then per-wave P slabs (32 rows)
    __shared__ f16 Ks[64 * SP];
    __shared__ f16 Vs[64 * SP];    // [d][key]

    {   // stage Q tile [q][dh]: 128 x 64 f16, 64 B per thread
        const int qrow = tid >> 1, qhalf = (tid & 1) * 32;
        const f16* src = Qh + ((size_t)bh * N_ + qb + qrow) * DH + qhalf;
#pragma unroll
        for (int k = 0; k < 4; k++)
            *(float4*)&QPs[qrow * SP + qhalf + k * 8] = *(const float4*)(src + k * 8);
    }
    __syncthreads();
    const half8 qf0a = *(const half8*)&QPs[(wave * 32 + l16) * SP + quad * 8];
    const half8 qf1a = *(const half8*)&QPs[(wave * 32 + l16) * SP + 32 + quad * 8];
    const half8 qf0b = *(const half8*)&QPs[(wave * 32 + 16 + l16) * SP + quad * 8];
    const half8 qf1b = *(const half8*)&QPs[(wave * 32 + 16 + l16) * SP + 32 + quad * 8];
    f16* Ps = QPs + wave * 32 * SP;   // wave-private 32 x SP

    const int qgA = qb + wave * 32 + l16;
    const int qgB = qgA + 16;
    const u64* arowA = Padj + (size_t)qgA * 32;
    const u64* arowB = Padj + (size_t)qgB * 32;

    floatx4 zz = {0.f, 0.f, 0.f, 0.f};
    half4v hz = {(f16)0.f, (f16)0.f, (f16)0.f, (f16)0.f};
    half4v totA[4] = {hz, hz, hz, hz}, totB[4] = {hz, hz, hz, hz};

    const int kvr = tid >> 2, kvs = (tid & 3) * 16;

    for (int ci = 0; ci < 2; ci++) {
        const int c = sp * 2 + ci;
        floatx4 chA[4] = {zz, zz, zz, zz}, chB[4] = {zz, zz, zz, zz};
        float rsA = 0.f, rsB = 0.f;

        for (int kt = 0; kt < 4; kt++) {
            const int k0 = c * 256 + kt * 64;
            const f16* ksrc = Kh + ((size_t)bh * N_ + k0 + kvr) * DH + kvs;
            const f16* vsrc = Vt + ((size_t)bh * DH + kvr) * N_ + k0 + kvs;
            float4 ka0 = *(const float4*)(ksrc), ka1 = *(const float4*)(ksrc + 8);
            float4 va0 = *(const float4*)(vsrc), va1 = *(const float4*)(vsrc + 8);
            __syncthreads();
            *(float4*)&Ks[kvr * SP + kvs]     = ka0;
            *(float4*)&Ks[kvr * SP + kvs + 8] = ka1;
            *(float4*)&Vs[kvr * SP + kvs]     = va0;
            *(float4*)&Vs[kvr * SP + kvs + 8] = va1;
            __syncthreads();

            const u64 awA = arowA[k0 >> 6];
            const u64 awB = arowB[k0 >> 6];
            float rA = 0.f, rB = 0.f;
#pragma unroll
            for (int m = 0; m < 4; m++) {
                half8 a0 = *(const half8*)&Ks[(m * 16 + l16) * SP + quad * 8];
                half8 a1 = *(const half8*)&Ks[(m * 16 + l16) * SP + 32 + quad * 8];
                floatx4 sA = zz, sB = zz;
                sA = __builtin_amdgcn_mfma_f32_16x16x32_f16(a0, qf0a, sA, 0, 0, 0);
                sA = __builtin_amdgcn_mfma_f32_16x16x32_f16(a1, qf1a, sA, 0, 0, 0);
                sB = __builtin_amdgcn_mfma_f32_16x16x32_f16(a0, qf0b, sB, 0, 0, 0);
                sB = __builtin_amdgcn_mfma_f32_16x16x32_f16(a1, qf1b, sB, 0, 0, 0);
                const unsigned int nibA = (unsigned int)(awA >> (m * 16 + quad * 4)) & 0xFu;
                const unsigned int nibB = (unsigned int)(awB >> (m * 16 + quad * 4)) & 0xFu;
                half4v pA, pB;
#pragma unroll
                for (int r = 0; r < 4; r++) {
                    float svA = fminf(fmaxf(sA[r], -CLIP), CLIP);
                    svA = ((nibA >> r) & 1u) ? svA : -CLIP;
                    const float eA = __builtin_amdgcn_exp2f(svA);
                    rA += eA; pA[r] = (f16)eA;
                    float svB = fminf(fmaxf(sB[r], -CLIP), CLIP);
                    svB = ((nibB >> r) & 1u) ? svB : -CLIP;
                    const float eB = __builtin_amdgcn_exp2f(svB);
                    rB += eB; pB[r] = (f16)eB;
                }
                *(half4v*)&Ps[l16 * SP + m * 16 + quad * 4]        = pA;
                *(half4v*)&Ps[(16 + l16) * SP + m * 16 + quad * 4] = pB;
            }
            rA += __shfl_xor(rA, 16); rA += __shfl_xor(rA, 32); rsA += rA;
            rB += __shfl_xor(rB, 16); rB += __shfl_xor(rB, 32); rsB += rB;

            const half8 pA0 = *(const half8*)&Ps[l16 * SP + quad * 8];
            const half8 pA1 = *(const half8*)&Ps[l16 * SP + 32 + quad * 8];
            const half8 pB0 = *(const half8*)&Ps[(16 + l16) * SP + quad * 8];
            const half8 pB1 = *(const half8*)&Ps[(16 + l16) * SP + 32 + quad * 8];
#pragma unroll
            for (int m = 0; m < 4; m++) {
                half8 va8 = *(const half8*)&Vs[(m * 16 + l16) * SP + quad * 8];
                half8 vb8 = *(const half8*)&Vs[(m * 16 + l16) * SP + 32 + quad * 8];
                chA[m] = __builtin_amdgcn_mfma_f32_16x16x32_f16(va8, pA0, chA[m], 0, 0, 0);
                chA[m] = __builtin_amdgcn_mfma_f32_16x16x32_f16(vb8, pA1, chA[m], 0, 0, 0);
                chB[m] = __builtin_amdgcn_mfma_f32_16x16x32_f16(va8, pB0, chB[m], 0, 0, 0);
                chB[m] = __builtin_amdgcn_mfma_f32_16x16x32_f16(vb8, pB1, chB[m], 0, 0, 0);
            }
        }

        // normalize this chunk and accumulate into packed-f16 totals
        const float invA = 1.0f / rsA, invB = 1.0f / rsB;
#pragma unroll
        for (int m = 0; m < 4; m++)
#pragma unroll
            for (int r = 0; r < 4; r++) {
                totA[m][r] = totA[m][r] + (f16)(chA[m][r] * invA);
                totB[m][r] = totB[m][r] + (f16)(chB[m][r] * invB);
            }
    }

    f16* dstA = CTXP + (((size_t)sp * B_ + b) * N_ + qgA) * F_ + h * DH;
    f16* dstB = CTXP + (((size_t)sp * B_ + b) * N_ + qgB) * F_ + h * DH;
#pragma unroll
    for (int m = 0; m < 4; m++) {
        *(half4v*)&dstA[m * 16 + quad * 4] = totA[m];
        *(half4v*)&dstB[m * 16 + quad * 4] = totB[m];
    }
}

// ---------------------------------------------------------------------------
// Kernel 3: fused [sum 4 partials] + [ctx @ Wo^T + bo + x] + LayerNorm.
// ---------------------------------------------------------------------------
__global__ __launch_bounds__(256) void out_mfma(
    const f16* __restrict__ CTXP, const float* __restrict__ x,
    const f16* __restrict__ Woh, const float* __restrict__ bo,
    const float* __restrict__ gamma, const float* __restrict__ beta,
    float* __restrict__ out)
{
    const int n0 = blockIdx.x * 16;
    const int tid  = threadIdx.x;
    const int wave = tid >> 6, lane = tid & 63;
    const int quad = lane >> 4, l16 = lane & 15;
    const int wrow = tid >> 2, wseg = tid & 3;

    __shared__ f16 cs[16 * SPW];
    __shared__ f16 wtile[256 * SP];
    __shared__ float red0[4][16], red1[4][16];

    {   // stage ctx rows: sum 4 f16 split-partials in fp32, store f16
        const int row = tid >> 4, c0 = (tid & 15) * 16;
        const size_t S = (size_t)BN * F_;
        const f16* p = CTXP + (size_t)(n0 + row) * F_ + c0;
#pragma unroll
        for (int g = 0; g < 2; g++) {
            half8 s0 = *(const half8*)(p + g * 8);
            half8 s1 = *(const half8*)(p + S + g * 8);
            half8 s2 = *(const half8*)(p + 2 * S + g * 8);
            half8 s3 = *(const half8*)(p + 3 * S + g * 8);
            half8 o;
#pragma unroll
            for (int e = 0; e < 8; e++)
                o[e] = (f16)(((float)s0[e] + (float)s1[e]) + ((float)s2[e] + (float)s3[e]));
            *(half8*)&cs[row * SPW + c0 + g * 8] = o;
        }
    }

    floatx4 zz = {0.f, 0.f, 0.f, 0.f};
    floatx4 acc[4] = {zz, zz, zz, zz};

#pragma unroll
    for (int f0 = 0; f0 < F_; f0 += 64) {
        __syncthreads();   // covers cs staging (iter 0) and prior frag reads
#pragma unroll
        for (int rr = 0; rr < 4; rr++) {
            const int o = rr * 64 + wrow;
            const f16* src = Woh + (size_t)o * F_ + f0 + wseg * 16;
            *(float4*)&wtile[o * SP + wseg * 16]     = *(const float4*)(src);
            *(float4*)&wtile[o * SP + wseg * 16 + 8] = *(const float4*)(src + 8);
        }
        __syncthreads();
        half8 a0 = *(const half8*)&cs[l16 * SPW + f0 + quad * 8];
        half8 a1 = *(const half8*)&cs[l16 * SPW + f0 + 32 + quad * 8];
#pragma unroll
        for (int ot = 0; ot < 4; ot++) {
            const int o = wave * 64 + ot * 16 + l16;
            half8 b0 = *(const half8*)&wtile[o * SP + quad * 8];
            half8 b1 = *(const half8*)&wtile[o * SP + 32 + quad * 8];
            acc[ot] = __builtin_amdgcn_mfma_f32_16x16x32_f16(a0, b0, acc[ot], 0, 0, 0);
            acc[ot] = __builtin_amdgcn_mfma_f32_16x16x32_f16(a1, b1, acc[ot], 0, 0, 0);
        }
    }

    // bias + residual
#pragma unroll
    for (int ot = 0; ot < 4; ot++) {
        const int o = wave * 64 + ot * 16 + l16;
        const float bo_ = bo[o];
#pragma unroll
        for (int r = 0; r < 4; r++)
            acc[ot][r] += bo_ + x[(size_t)(n0 + quad * 4 + r) * F_ + o];
    }

    // per-row partial sums over this wave's 64 cols
#pragma unroll
    for (int r = 0; r < 4; r++) {
        float s = (acc[0][r] + acc[1][r]) + (acc[2][r] + acc[3][r]);
        float q = (acc[0][r] * acc[0][r] + acc[1][r] * acc[1][r]) +
                  (acc[2][r] * acc[2][r] + acc[3][r] * acc[3][r]);
        s += __shfl_xor(s, 1); q += __shfl_xor(q, 1);
        s += __shfl_xor(s, 2); q += __shfl_xor(q, 2);
        s += __shfl_xor(s, 4); q += __shfl_xor(q, 4);
        s += __shfl_xor(s, 8); q += __shfl_xor(q, 8);
        if (l16 == 0) { red0[wave][quad * 4 + r] = s; red1[wave][quad * 4 + r] = q; }
    }
    __syncthreads();

#pragma unroll
    for (int r = 0; r < 4; r++) {
        const int rr = quad * 4 + r;
        const float S  = (red0[0][rr] + red0[1][rr]) + (red0[2][rr] + red0[3][rr]);
        const float Q2 = (red1[0][rr] + red1[1][rr]) + (red1[2][rr] + red1[3][rr]);
        const float mu  = S * (1.0f / F_);
        const float var = Q2 * (1.0f / F_) - mu * mu;
        const float inv = rsqrtf(var + 1e-5f);
#pragma unroll
        for (int ot = 0; ot < 4; ot++) {
            const int o = wave * 64 + ot * 16 + l16;
            out[(size_t)(n0 + rr) * F_ + o] =
                (acc[ot][r] - mu) * inv * gamma[o] + beta[o];
        }
    }
}

// ---------------------------------------------------------------------------
extern "C" void kernel_launch(void* const* d_in, const int* in_sizes, int n_in,
                              void* d_out, int out_size, void* d_ws, size_t ws_size,
                              hipStream_t stream)
{
    const float* x     = (const float*)d_in[0];
    const int*   adj   = (const int*)  d_in[1];
    const float* Wq    = (const float*)d_in[2];
    const float* bq    = (const float*)d_in[3];
    const float* Wk    = (const float*)d_in[4];
    const float* bk    = (const float*)d_in[5];
    const float* Wv    = (const float*)d_in[6];
    const float* bv    = (const float*)d_in[7];
    const float* Wo    = (const float*)d_in[8];
    const float* bo    = (const float*)d_in[9];
    const float* gamma = (const float*)d_in[10];
    const float* beta  = (const float*)d_in[11];
    float* out = (float*)d_out;

    float* ws = (float*)d_ws;
    f16*   CTXP = (f16*)(ws);                       // 8M halves (4,194,304 fl)
    f16*   Qh   = (f16*)(ws + 4194304);             // 2M halves
    f16*   Kh   = (f16*)(ws + 5242880);
    f16*   Vt   = (f16*)(ws + 6291456);
    u64*   Padj = (u64*)(ws + 7340032);             // 512 KB
    f16*   Woh  = (f16*)(ws + 7471104);             // 64K halves

    hipLaunchKernelGGL(proj_fused, dim3(8608), dim3(512), 0, stream,
                       x, Wq, Wk, Wv, bq, bk, bv, adj, Padj, Wo, Woh, Qh, Kh, Vt);
    hipLaunchKernelGGL(attn_mfma, dim3(64, H_, B_), dim3(256), 0, stream,
                       Qh, Kh, Vt, Padj, CTXP);
    hipLaunchKernelGGL(out_mfma, dim3(BN / 16), dim3(256), 0, stream,
                       CTXP, x, Woh, bo, gamma, beta, out);
}

// Round 12
// 156.279 us; speedup vs baseline: 1.0823x; 1.0823x over previous
//
#include <hip/hip_runtime.h>
#include <math.h>

#define B_     4
#define N_     2048
#define F_     256
#define H_     4
#define DH     64
#define BN     8192
#define SP     72    // padded f16 stride (64 + 8) -> 144 B
#define SPO    136   // padded f16 stride for proj epilogue (128 + 8)
#define SPW    264   // padded f16 stride for out-kernel ctx rows

#define QSCALE 0.18033688011112042f   // 0.125 * log2(e)
#define CLIP   14.426950408889634f    // 10 * log2(e)

typedef _Float16 f16;
typedef _Float16 half8  __attribute__((ext_vector_type(8)));
typedef _Float16 half4v __attribute__((ext_vector_type(4)));
typedef float    floatx4 __attribute__((ext_vector_type(4)));
typedef unsigned long long u64;

// ---------------------------------------------------------------------------
// Kernel 0: fused prep — pack adj to bits + convert x/Wq/Wk/Wv/Wo to f16.
// ---------------------------------------------------------------------------
__global__ __launch_bounds__(256) void prep_kernel(
    const int* __restrict__ adj, u64* __restrict__ P,
    const float* __restrict__ x,  f16* __restrict__ xh,
    const float* __restrict__ Wq, f16* __restrict__ Wqh,
    const float* __restrict__ Wk, f16* __restrict__ Wkh,
    const float* __restrict__ Wv, f16* __restrict__ Wvh,
    const float* __restrict__ Wo, f16* __restrict__ Woh)
{
    const int bid = blockIdx.x;
    if (bid < 16384) {
        const int row   = bid >> 3;
        const int chunk = bid & 7;
        const int wave  = threadIdx.x >> 6, lane = threadIdx.x & 63;
        const int key   = chunk * 256 + wave * 64 + lane;
        u64 m = __ballot(adj[(size_t)row * N_ + key] != 0);
        if (lane == 0) P[(size_t)row * 32 + chunk * 4 + wave] = m;
        return;
    }
    const float* src; f16* dst; int base;
    if      (bid < 16448) { src = Wo; dst = Woh; base = (bid - 16384) * 1024; }
    else if (bid < 16512) { src = Wq; dst = Wqh; base = (bid - 16448) * 1024; }
    else if (bid < 16576) { src = Wk; dst = Wkh; base = (bid - 16512) * 1024; }
    else if (bid < 16640) { src = Wv; dst = Wvh; base = (bid - 16576) * 1024; }
    else                  { src = x;  dst = xh;  base = (bid - 16640) * 1024; }
    const int idx = base + threadIdx.x * 4;
    float4 v = *(const float4*)(src + idx);
    half4v h; h[0] = (f16)v.x; h[1] = (f16)v.y; h[2] = (f16)v.z; h[3] = (f16)v.w;
    *(half4v*)(dst + idx) = h;
}

// ---------------------------------------------------------------------------
// Kernel 1: QKV projection via MFMA, all-f16 inputs.  64n x 128o tile,
// 256 threads; wave owns 16n x 128o.  Q pre-scaled; V stored transposed
// direct from C-regs.
// ---------------------------------------------------------------------------
__global__ __launch_bounds__(256) void proj_mfma(
    const f16* __restrict__ xh,
    const f16* __restrict__ Wqh, const f16* __restrict__ Wkh, const f16* __restrict__ Wvh,
    const float* __restrict__ bq, const float* __restrict__ bk, const float* __restrict__ bv,
    f16* __restrict__ Qh, f16* __restrict__ Kh, f16* __restrict__ Vt)
{
    const int which = blockIdx.z;
    const f16*   W    = which == 0 ? Wqh : which == 1 ? Wkh : Wvh;
    const float* bias = which == 0 ? bq  : which == 1 ? bk  : bv;

    const int r0 = blockIdx.x * 64;
    const int c0 = blockIdx.y * 128;
    const int tid  = threadIdx.x;
    const int wave = tid >> 6, lane = tid & 63;
    const int quad = lane >> 4, l16 = lane & 15;
    const int row  = tid >> 2, seg  = tid & 3;          // x staging: 64 rows
    const int wrow = tid >> 1, whalf = (tid & 1) * 32;  // W staging: 128 rows

    __shared__ f16 smem[(64 + 128) * SP];
    f16* xs = smem;
    f16* wt = smem + 64 * SP;

    floatx4 zz = {0.f, 0.f, 0.f, 0.f};
    floatx4 acc[8] = {zz, zz, zz, zz, zz, zz, zz, zz};

    for (int f0 = 0; f0 < F_; f0 += 64) {
        const f16* xsrc = xh + (size_t)(r0 + row) * F_ + f0 + seg * 16;
        const f16* wsrc = W  + (size_t)(c0 + wrow) * F_ + f0 + whalf;
        float4 xa0 = *(const float4*)(xsrc),      xa1 = *(const float4*)(xsrc + 8);
        float4 wa0 = *(const float4*)(wsrc),      wa1 = *(const float4*)(wsrc + 8);
        float4 wa2 = *(const float4*)(wsrc + 16), wa3 = *(const float4*)(wsrc + 24);
        __syncthreads();
        *(float4*)&xs[row * SP + seg * 16]      = xa0;
        *(float4*)&xs[row * SP + seg * 16 + 8]  = xa1;
        *(float4*)&wt[wrow * SP + whalf]        = wa0;
        *(float4*)&wt[wrow * SP + whalf + 8]    = wa1;
        *(float4*)&wt[wrow * SP + whalf + 16]   = wa2;
        *(float4*)&wt[wrow * SP + whalf + 24]   = wa3;
        __syncthreads();
        half8 a0 = *(const half8*)&xs[(wave * 16 + l16) * SP + quad * 8];
        half8 a1 = *(const half8*)&xs[(wave * 16 + l16) * SP + 32 + quad * 8];
#pragma unroll
        for (int ot = 0; ot < 8; ot++) {
            half8 b0 = *(const half8*)&wt[(ot * 16 + l16) * SP + quad * 8];
            half8 b1 = *(const half8*)&wt[(ot * 16 + l16) * SP + 32 + quad * 8];
            acc[ot] = __builtin_amdgcn_mfma_f32_16x16x32_f16(a0, b0, acc[ot], 0, 0, 0);
            acc[ot] = __builtin_amdgcn_mfma_f32_16x16x32_f16(a1, b1, acc[ot], 0, 0, 0);
        }
    }

    const int bb = r0 >> 11, nn0 = r0 & (N_ - 1);

    if (which == 2) {
#pragma unroll
        for (int ot = 0; ot < 8; ot++) {
            const int o  = c0 + ot * 16 + l16;
            const int hy = o >> 6, dh = o & 63;
            const float bv_ = bias[o];
            half4v h4;
#pragma unroll
            for (int r = 0; r < 4; r++) h4[r] = (f16)(acc[ot][r] + bv_);
            *(half4v*)(Vt + (((size_t)bb * H_ + hy) * DH + dh) * N_
                          + nn0 + wave * 16 + quad * 4) = h4;
        }
    } else {
        const float scl = (which == 0) ? QSCALE : 1.0f;
        f16* dst = which == 0 ? Qh : Kh;
        __syncthreads();
        f16* outb = smem;   // 64 x SPO
#pragma unroll
        for (int ot = 0; ot < 8; ot++) {
            const float bv_ = bias[c0 + ot * 16 + l16];
#pragma unroll
            for (int r = 0; r < 4; r++)
                outb[(wave * 16 + quad * 4 + r) * SPO + ot * 16 + l16] =
                    (f16)((acc[ot][r] + bv_) * scl);
        }
        __syncthreads();
        const int colb = seg * 32;
        const int hh = (c0 + colb) >> 6, dcol = (c0 + colb) & 63;
        f16* g = dst + (((size_t)bb * H_ + hh) * N_ + nn0 + row) * DH + dcol;
#pragma unroll
        for (int k = 0; k < 4; k++)
            *(float4*)(g + k * 8) = *(const float4*)&outb[row * SPO + colb + k * 8];
    }
}

// ---------------------------------------------------------------------------
// Kernel 2: MFMA chunked attention — 512 threads (8 waves), 128 q per block,
// wave owns 16 q; chunk-split x4 (2 chunks per block).  [R8 config: the
// measured-best attn/total combination.]
// ---------------------------------------------------------------------------
__global__ __launch_bounds__(512) void attn_mfma(
    const f16* __restrict__ Qh, const f16* __restrict__ Kh,
    const f16* __restrict__ Vt, const u64* __restrict__ Padj,
    f16* __restrict__ CTXP)
{
    const int nt = blockIdx.x & 15;
    const int sp = blockIdx.x >> 4;        // split 0..3 (2 chunks each)
    const int qb = nt * 128;
    const int h  = blockIdx.y;
    const int b  = blockIdx.z;
    const int bh = b * H_ + h;
    const int tid  = threadIdx.x;
    const int wave = tid >> 6, lane = tid & 63;
    const int quad = lane >> 4, l16 = lane & 15;
    const int qrow = tid >> 2, qseg = tid & 3;     // Q staging: 128 rows
    const int kvr  = tid >> 3, kvs  = tid & 7;     // K/V staging: 64 rows

    __shared__ f16 QPs[128 * SP];  // Q stage, then per-wave P slabs (16 rows)
    __shared__ f16 Ks[64 * SP];
    __shared__ f16 Vs[64 * SP];    // [d][key]

    {   // stage Q tile [q][dh]
        const f16* src = Qh + ((size_t)bh * N_ + qb + qrow) * DH + qseg * 16;
        *(float4*)&QPs[qrow * SP + qseg * 16]     = *(const float4*)(src);
        *(float4*)&QPs[qrow * SP + qseg * 16 + 8] = *(const float4*)(src + 8);
    }
    __syncthreads();
    const half8 qf0 = *(const half8*)&QPs[(wave * 16 + l16) * SP + quad * 8];
    const half8 qf1 = *(const half8*)&QPs[(wave * 16 + l16) * SP + 32 + quad * 8];
    f16* Ps = QPs + wave * 16 * SP;   // wave-private 16 x SP

    const int qglob = qb + wave * 16 + l16;
    const u64* arow = Padj + (size_t)qglob * 32;

    floatx4 zz = {0.f, 0.f, 0.f, 0.f};
    floatx4 ctx_tot[4] = {zz, zz, zz, zz};

    for (int ci = 0; ci < 2; ci++) {
        const int c = sp * 2 + ci;
        floatx4 ctx_ch[4] = {zz, zz, zz, zz};
        float rs_ch = 0.f;

        for (int kt = 0; kt < 4; kt++) {
            const int k0 = c * 256 + kt * 64;
            const f16* ksrc = Kh + ((size_t)bh * N_ + k0 + kvr) * DH + kvs * 8;
            const f16* vsrc = Vt + ((size_t)bh * DH + kvr) * N_ + k0 + kvs * 8;
            float4 ka = *(const float4*)(ksrc);
            float4 va = *(const float4*)(vsrc);
            __syncthreads();
            *(float4*)&Ks[kvr * SP + kvs * 8] = ka;
            *(float4*)&Vs[kvr * SP + kvs * 8] = va;
            __syncthreads();

            const u64 aw = arow[k0 >> 6];
            float rs = 0.f;
#pragma unroll
            for (int m = 0; m < 4; m++) {
                floatx4 sacc = zz;
                half8 a0 = *(const half8*)&Ks[(m * 16 + l16) * SP + quad * 8];
                half8 a1 = *(const half8*)&Ks[(m * 16 + l16) * SP + 32 + quad * 8];
                sacc = __builtin_amdgcn_mfma_f32_16x16x32_f16(a0, qf0, sacc, 0, 0, 0);
                sacc = __builtin_amdgcn_mfma_f32_16x16x32_f16(a1, qf1, sacc, 0, 0, 0);
                const unsigned int nib = (unsigned int)(aw >> (m * 16 + quad * 4)) & 0xFu;
                half4v pv;
#pragma unroll
                for (int r = 0; r < 4; r++) {
                    float sv = fminf(fmaxf(sacc[r], -CLIP), CLIP);
                    sv = ((nib >> r) & 1u) ? sv : -CLIP;
                    const float ev = __builtin_amdgcn_exp2f(sv);
                    rs += ev;
                    pv[r] = (f16)ev;
                }
                *(half4v*)&Ps[l16 * SP + m * 16 + quad * 4] = pv;
            }
            rs += __shfl_xor(rs, 16);
            rs += __shfl_xor(rs, 32);
            rs_ch += rs;

            const half8 p0 = *(const half8*)&Ps[l16 * SP + quad * 8];
            const half8 p1 = *(const half8*)&Ps[l16 * SP + 32 + quad * 8];
#pragma unroll
            for (int m = 0; m < 4; m++) {
                half8 va8 = *(const half8*)&Vs[(m * 16 + l16) * SP + quad * 8];
                half8 vb8 = *(const half8*)&Vs[(m * 16 + l16) * SP + 32 + quad * 8];
                ctx_ch[m] = __builtin_amdgcn_mfma_f32_16x16x32_f16(va8, p0, ctx_ch[m], 0, 0, 0);
                ctx_ch[m] = __builtin_amdgcn_mfma_f32_16x16x32_f16(vb8, p1, ctx_ch[m], 0, 0, 0);
            }
        }

        const float inv = 1.0f / rs_ch;
#pragma unroll
        for (int m = 0; m < 4; m++)
#pragma unroll
            for (int r = 0; r < 4; r++)
                ctx_tot[m][r] += ctx_ch[m][r] * inv;
    }

    f16* dst = CTXP + (((size_t)sp * B_ + b) * N_ + qglob) * F_ + h * DH;
#pragma unroll
    for (int m = 0; m < 4; m++) {
        half4v h4;
#pragma unroll
        for (int r = 0; r < 4; r++) h4[r] = (f16)ctx_tot[m][r];
        *(half4v*)&dst[m * 16 + quad * 4] = h4;
    }
}

// ---------------------------------------------------------------------------
// Kernel 3: fused [sum 4 partials] + [ctx @ Wo^T + bo + x] + LayerNorm.
// 32 rows per block (halves Wo re-staging vs the 16-row version); Wo
// fragment reads hoisted over both row-groups.
// ---------------------------------------------------------------------------
__global__ __launch_bounds__(256) void out_mfma(
    const f16* __restrict__ CTXP, const float* __restrict__ x,
    const f16* __restrict__ Woh, const float* __restrict__ bo,
    const float* __restrict__ gamma, const float* __restrict__ beta,
    float* __restrict__ out)
{
    const int n0 = blockIdx.x * 32;
    const int tid  = threadIdx.x;
    const int wave = tid >> 6, lane = tid & 63;
    const int quad = lane >> 4, l16 = lane & 15;
    const int wrow = tid >> 2, wseg = tid & 3;

    __shared__ f16 cs[32 * SPW];
    __shared__ f16 wtile[256 * SP];
    __shared__ float red0[4][32], red1[4][32];

    {   // stage ctx rows: sum 4 f16 split-partials in fp32, store f16
        const int row = tid >> 4, c0 = (tid & 15) * 16;
        const size_t S = (size_t)BN * F_;
#pragma unroll
        for (int g2 = 0; g2 < 2; g2++) {
            const int rr = g2 * 16 + row;
            const f16* p = CTXP + (size_t)(n0 + rr) * F_ + c0;
#pragma unroll
            for (int g = 0; g < 2; g++) {
                half8 s0 = *(const half8*)(p + g * 8);
                half8 s1 = *(const half8*)(p + S + g * 8);
                half8 s2 = *(const half8*)(p + 2 * S + g * 8);
                half8 s3 = *(const half8*)(p + 3 * S + g * 8);
                half8 o;
#pragma unroll
                for (int e = 0; e < 8; e++)
                    o[e] = (f16)(((float)s0[e] + (float)s1[e]) + ((float)s2[e] + (float)s3[e]));
                *(half8*)&cs[rr * SPW + c0 + g * 8] = o;
            }
        }
    }

    floatx4 zz = {0.f, 0.f, 0.f, 0.f};
    floatx4 acc[2][4] = {{zz, zz, zz, zz}, {zz, zz, zz, zz}};

#pragma unroll
    for (int f0 = 0; f0 < F_; f0 += 64) {
        __syncthreads();   // covers cs staging (iter 0) and prior frag reads
#pragma unroll
        for (int rr = 0; rr < 4; rr++) {
            const int o = rr * 64 + wrow;
            const f16* src = Woh + (size_t)o * F_ + f0 + wseg * 16;
            *(float4*)&wtile[o * SP + wseg * 16]     = *(const float4*)(src);
            *(float4*)&wtile[o * SP + wseg * 16 + 8] = *(const float4*)(src + 8);
        }
        __syncthreads();
        half8 a00 = *(const half8*)&cs[l16 * SPW + f0 + quad * 8];
        half8 a01 = *(const half8*)&cs[l16 * SPW + f0 + 32 + quad * 8];
        half8 a10 = *(const half8*)&cs[(16 + l16) * SPW + f0 + quad * 8];
        half8 a11 = *(const half8*)&cs[(16 + l16) * SPW + f0 + 32 + quad * 8];
#pragma unroll
        for (int ot = 0; ot < 4; ot++) {
            const int o = wave * 64 + ot * 16 + l16;
            half8 b0 = *(const half8*)&wtile[o * SP + quad * 8];
            half8 b1 = *(const half8*)&wtile[o * SP + 32 + quad * 8];
            acc[0][ot] = __builtin_amdgcn_mfma_f32_16x16x32_f16(a00, b0, acc[0][ot], 0, 0, 0);
            acc[0][ot] = __builtin_amdgcn_mfma_f32_16x16x32_f16(a01, b1, acc[0][ot], 0, 0, 0);
            acc[1][ot] = __builtin_amdgcn_mfma_f32_16x16x32_f16(a10, b0, acc[1][ot], 0, 0, 0);
            acc[1][ot] = __builtin_amdgcn_mfma_f32_16x16x32_f16(a11, b1, acc[1][ot], 0, 0, 0);
        }
    }

    // bias + residual
#pragma unroll
    for (int g2 = 0; g2 < 2; g2++)
#pragma unroll
        for (int ot = 0; ot < 4; ot++) {
            const int o = wave * 64 + ot * 16 + l16;
            const float bo_ = bo[o];
#pragma unroll
            for (int r = 0; r < 4; r++)
                acc[g2][ot][r] += bo_ + x[(size_t)(n0 + g2 * 16 + quad * 4 + r) * F_ + o];
        }

    // per-row partial sums over this wave's 64 cols
#pragma unroll
    for (int g2 = 0; g2 < 2; g2++)
#pragma unroll
        for (int r = 0; r < 4; r++) {
            float s = (acc[g2][0][r] + acc[g2][1][r]) + (acc[g2][2][r] + acc[g2][3][r]);
            float q = (acc[g2][0][r] * acc[g2][0][r] + acc[g2][1][r] * acc[g2][1][r]) +
                      (acc[g2][2][r] * acc[g2][2][r] + acc[g2][3][r] * acc[g2][3][r]);
            s += __shfl_xor(s, 1); q += __shfl_xor(q, 1);
            s += __shfl_xor(s, 2); q += __shfl_xor(q, 2);
            s += __shfl_xor(s, 4); q += __shfl_xor(q, 4);
            s += __shfl_xor(s, 8); q += __shfl_xor(q, 8);
            if (l16 == 0) {
                red0[wave][g2 * 16 + quad * 4 + r] = s;
                red1[wave][g2 * 16 + quad * 4 + r] = q;
            }
        }
    __syncthreads();

#pragma unroll
    for (int g2 = 0; g2 < 2; g2++)
#pragma unroll
        for (int r = 0; r < 4; r++) {
            const int rr = g2 * 16 + quad * 4 + r;
            const float S  = (red0[0][rr] + red0[1][rr]) + (red0[2][rr] + red0[3][rr]);
            const float Q2 = (red1[0][rr] + red1[1][rr]) + (red1[2][rr] + red1[3][rr]);
            const float mu  = S * (1.0f / F_);
            const float var = Q2 * (1.0f / F_) - mu * mu;
            const float inv = rsqrtf(var + 1e-5f);
#pragma unroll
            for (int ot = 0; ot < 4; ot++) {
                const int o = wave * 64 + ot * 16 + l16;
                out[(size_t)(n0 + rr) * F_ + o] =
                    (acc[g2][ot][r] - mu) * inv * gamma[o] + beta[o];
            }
        }
}

// ---------------------------------------------------------------------------
extern "C" void kernel_launch(void* const* d_in, const int* in_sizes, int n_in,
                              void* d_out, int out_size, void* d_ws, size_t ws_size,
                              hipStream_t stream)
{
    const float* x     = (const float*)d_in[0];
    const int*   adj   = (const int*)  d_in[1];
    const float* Wq    = (const float*)d_in[2];
    const float* bq    = (const float*)d_in[3];
    const float* Wk    = (const float*)d_in[4];
    const float* bk    = (const float*)d_in[5];
    const float* Wv    = (const float*)d_in[6];
    const float* bv    = (const float*)d_in[7];
    const float* Wo    = (const float*)d_in[8];
    const float* bo    = (const float*)d_in[9];
    const float* gamma = (const float*)d_in[10];
    const float* beta  = (const float*)d_in[11];
    float* out = (float*)d_out;

    float* ws = (float*)d_ws;
    f16*   CTXP = (f16*)(ws);                       // 8M halves (4,194,304 fl)
    f16*   Qh   = (f16*)(ws + 4194304);             // 2M halves
    f16*   Kh   = (f16*)(ws + 5242880);
    f16*   Vt   = (f16*)(ws + 6291456);
    u64*   Padj = (u64*)(ws + 7340032);             // 512 KB
    f16*   Woh  = (f16*)(ws + 7471104);             // 64K halves
    // Overlays inside the CTXP region: consumed by proj BEFORE attn writes CTXP.
    f16*   xh   = CTXP;                             // 2M halves
    f16*   Wqh  = (f16*)(ws + 1048576);
    f16*   Wkh  = (f16*)(ws + 1081344);
    f16*   Wvh  = (f16*)(ws + 1114112);

    hipLaunchKernelGGL(prep_kernel, dim3(18688), dim3(256), 0, stream,
                       adj, Padj, x, xh, Wq, Wqh, Wk, Wkh, Wv, Wvh, Wo, Woh);
    hipLaunchKernelGGL(proj_mfma, dim3(BN / 64, 2, 3), dim3(256), 0, stream,
                       xh, Wqh, Wkh, Wvh, bq, bk, bv, Qh, Kh, Vt);
    hipLaunchKernelGGL(attn_mfma, dim3(64, H_, B_), dim3(512), 0, stream,
                       Qh, Kh, Vt, Padj, CTXP);
    hipLaunchKernelGGL(out_mfma, dim3(BN / 32), dim3(256), 0, stream,
                       CTXP, x, Woh, bo, gamma, beta, out);
}

// Round 13
// 154.747 us; speedup vs baseline: 1.0930x; 1.0099x over previous
//
#include <hip/hip_runtime.h>
#include <math.h>

#define B_     4
#define N_     2048
#define F_     256
#define H_     4
#define DH     64
#define BN     8192
#define SP     72    // padded f16 stride (64 + 8) -> 144 B
#define SPO    136   // padded f16 stride for proj epilogue (128 + 8)
#define SPW    264   // padded f16 stride for out-kernel ctx rows

#define QSCALE 0.18033688011112042f   // 0.125 * log2(e)
#define CLIP   14.426950408889634f    // 10 * log2(e)

typedef _Float16 f16;
typedef _Float16 half8  __attribute__((ext_vector_type(8)));
typedef _Float16 half4v __attribute__((ext_vector_type(4)));
typedef float    floatx4  __attribute__((ext_vector_type(4)));
typedef float    floatx16 __attribute__((ext_vector_type(16)));
typedef unsigned long long u64;

// ---------------------------------------------------------------------------
// Kernel 0: fused prep — pack adj to bits + convert x/Wq/Wk/Wv/Wo to f16.
// ---------------------------------------------------------------------------
__global__ __launch_bounds__(256) void prep_kernel(
    const int* __restrict__ adj, u64* __restrict__ P,
    const float* __restrict__ x,  f16* __restrict__ xh,
    const float* __restrict__ Wq, f16* __restrict__ Wqh,
    const float* __restrict__ Wk, f16* __restrict__ Wkh,
    const float* __restrict__ Wv, f16* __restrict__ Wvh,
    const float* __restrict__ Wo, f16* __restrict__ Woh)
{
    const int bid = blockIdx.x;
    if (bid < 16384) {
        const int row   = bid >> 3;
        const int chunk = bid & 7;
        const int wave  = threadIdx.x >> 6, lane = threadIdx.x & 63;
        const int key   = chunk * 256 + wave * 64 + lane;
        u64 m = __ballot(adj[(size_t)row * N_ + key] != 0);
        if (lane == 0) P[(size_t)row * 32 + chunk * 4 + wave] = m;
        return;
    }
    const float* src; f16* dst; int base;
    if      (bid < 16448) { src = Wo; dst = Woh; base = (bid - 16384) * 1024; }
    else if (bid < 16512) { src = Wq; dst = Wqh; base = (bid - 16448) * 1024; }
    else if (bid < 16576) { src = Wk; dst = Wkh; base = (bid - 16512) * 1024; }
    else if (bid < 16640) { src = Wv; dst = Wvh; base = (bid - 16576) * 1024; }
    else                  { src = x;  dst = xh;  base = (bid - 16640) * 1024; }
    const int idx = base + threadIdx.x * 4;
    float4 v = *(const float4*)(src + idx);
    half4v h; h[0] = (f16)v.x; h[1] = (f16)v.y; h[2] = (f16)v.z; h[3] = (f16)v.w;
    *(half4v*)(dst + idx) = h;
}

// ---------------------------------------------------------------------------
// Kernel 1: QKV projection via MFMA, all-f16 inputs (R12-proven version).
// ---------------------------------------------------------------------------
__global__ __launch_bounds__(256) void proj_mfma(
    const f16* __restrict__ xh,
    const f16* __restrict__ Wqh, const f16* __restrict__ Wkh, const f16* __restrict__ Wvh,
    const float* __restrict__ bq, const float* __restrict__ bk, const float* __restrict__ bv,
    f16* __restrict__ Qh, f16* __restrict__ Kh, f16* __restrict__ Vt)
{
    const int which = blockIdx.z;
    const f16*   W    = which == 0 ? Wqh : which == 1 ? Wkh : Wvh;
    const float* bias = which == 0 ? bq  : which == 1 ? bk  : bv;

    const int r0 = blockIdx.x * 64;
    const int c0 = blockIdx.y * 128;
    const int tid  = threadIdx.x;
    const int wave = tid >> 6, lane = tid & 63;
    const int quad = lane >> 4, l16 = lane & 15;
    const int row  = tid >> 2, seg  = tid & 3;
    const int wrow = tid >> 1, whalf = (tid & 1) * 32;

    __shared__ f16 smem[(64 + 128) * SP];
    f16* xs = smem;
    f16* wt = smem + 64 * SP;

    floatx4 zz = {0.f, 0.f, 0.f, 0.f};
    floatx4 acc[8] = {zz, zz, zz, zz, zz, zz, zz, zz};

    for (int f0 = 0; f0 < F_; f0 += 64) {
        const f16* xsrc = xh + (size_t)(r0 + row) * F_ + f0 + seg * 16;
        const f16* wsrc = W  + (size_t)(c0 + wrow) * F_ + f0 + whalf;
        float4 xa0 = *(const float4*)(xsrc),      xa1 = *(const float4*)(xsrc + 8);
        float4 wa0 = *(const float4*)(wsrc),      wa1 = *(const float4*)(wsrc + 8);
        float4 wa2 = *(const float4*)(wsrc + 16), wa3 = *(const float4*)(wsrc + 24);
        __syncthreads();
        *(float4*)&xs[row * SP + seg * 16]      = xa0;
        *(float4*)&xs[row * SP + seg * 16 + 8]  = xa1;
        *(float4*)&wt[wrow * SP + whalf]        = wa0;
        *(float4*)&wt[wrow * SP + whalf + 8]    = wa1;
        *(float4*)&wt[wrow * SP + whalf + 16]   = wa2;
        *(float4*)&wt[wrow * SP + whalf + 24]   = wa3;
        __syncthreads();
        half8 a0 = *(const half8*)&xs[(wave * 16 + l16) * SP + quad * 8];
        half8 a1 = *(const half8*)&xs[(wave * 16 + l16) * SP + 32 + quad * 8];
#pragma unroll
        for (int ot = 0; ot < 8; ot++) {
            half8 b0 = *(const half8*)&wt[(ot * 16 + l16) * SP + quad * 8];
            half8 b1 = *(const half8*)&wt[(ot * 16 + l16) * SP + 32 + quad * 8];
            acc[ot] = __builtin_amdgcn_mfma_f32_16x16x32_f16(a0, b0, acc[ot], 0, 0, 0);
            acc[ot] = __builtin_amdgcn_mfma_f32_16x16x32_f16(a1, b1, acc[ot], 0, 0, 0);
        }
    }

    const int bb = r0 >> 11, nn0 = r0 & (N_ - 1);

    if (which == 2) {
#pragma unroll
        for (int ot = 0; ot < 8; ot++) {
            const int o  = c0 + ot * 16 + l16;
            const int hy = o >> 6, dh = o & 63;
            const float bv_ = bias[o];
            half4v h4;
#pragma unroll
            for (int r = 0; r < 4; r++) h4[r] = (f16)(acc[ot][r] + bv_);
            *(half4v*)(Vt + (((size_t)bb * H_ + hy) * DH + dh) * N_
                          + nn0 + wave * 16 + quad * 4) = h4;
        }
    } else {
        const float scl = (which == 0) ? QSCALE : 1.0f;
        f16* dst = which == 0 ? Qh : Kh;
        __syncthreads();
        f16* outb = smem;   // 64 x SPO
#pragma unroll
        for (int ot = 0; ot < 8; ot++) {
            const float bv_ = bias[c0 + ot * 16 + l16];
#pragma unroll
            for (int r = 0; r < 4; r++)
                outb[(wave * 16 + quad * 4 + r) * SPO + ot * 16 + l16] =
                    (f16)((acc[ot][r] + bv_) * scl);
        }
        __syncthreads();
        const int colb = seg * 32;
        const int hh = (c0 + colb) >> 6, dcol = (c0 + colb) & 63;
        f16* g = dst + (((size_t)bb * H_ + hh) * N_ + nn0 + row) * DH + dcol;
#pragma unroll
        for (int k = 0; k < 4; k++)
            *(float4*)(g + k * 8) = *(const float4*)&outb[row * SPO + colb + k * 8];
    }
}

// ---------------------------------------------------------------------------
// Kernel 2: MFMA chunked attention with 32x32x16 MFMA.  256 thr (4 waves),
// wave owns 32 q, 128 q per block, ONE chunk per block (split x8).
// A-frags cover 32 rows per b128 read -> ~0.69x LDS instr of the 16x16 path.
// C/D layout: col=lane&31, row=(reg&3)+8*(reg>>2)+4*(lane>>5)  [verified].
// ---------------------------------------------------------------------------
__global__ __launch_bounds__(256) void attn_mfma(
    const f16* __restrict__ Qh, const f16* __restrict__ Kh,
    const f16* __restrict__ Vt, const u64* __restrict__ Padj,
    f16* __restrict__ CTXP)
{
    const int nt = blockIdx.x & 15;
    const int sp = blockIdx.x >> 4;        // chunk 0..7
    const int qb = nt * 128;
    const int h  = blockIdx.y;
    const int b  = blockIdx.z;
    const int bh = b * H_ + h;
    const int tid  = threadIdx.x;
    const int wave = tid >> 6, lane = tid & 63;
    const int l31 = lane & 31, hf = lane >> 5;

    __shared__ f16 QPs[128 * SP];  // Q stage, then per-wave P slabs (32 rows)
    __shared__ f16 Ks[64 * SP];    // [key][dh]
    __shared__ f16 Vs[64 * SP];    // [d][key]

    {   // stage Q tile [q][dh]: 128 x 64 f16
        const int qrow = tid >> 1, qhalf = (tid & 1) * 32;
        const f16* src = Qh + ((size_t)bh * N_ + qb + qrow) * DH + qhalf;
#pragma unroll
        for (int k = 0; k < 4; k++)
            *(float4*)&QPs[qrow * SP + qhalf + k * 8] = *(const float4*)(src + k * 8);
    }
    __syncthreads();
    // Q B-frags (B[k=dh][n=q]: n=l31, k=hf*8+j within each 16-dh step)
    half8 qf[4];
#pragma unroll
    for (int s = 0; s < 4; s++)
        qf[s] = *(const half8*)&QPs[(wave * 32 + l31) * SP + s * 16 + hf * 8];
    f16* Ps = QPs + wave * 32 * SP;   // wave-private 32 x SP  [q][key]

    const int qglob = qb + wave * 32 + l31;
    const u64* arow = Padj + (size_t)qglob * 32;

    floatx16 ctx0 = {0.f,0.f,0.f,0.f,0.f,0.f,0.f,0.f,0.f,0.f,0.f,0.f,0.f,0.f,0.f,0.f};
    floatx16 ctx1 = ctx0;
    const floatx16 z16 = ctx0;
    float rs_ch = 0.f;

    const int kvr = tid >> 2, kvs = (tid & 3) * 16;

    for (int kt = 0; kt < 4; kt++) {
        const int k0 = sp * 256 + kt * 64;
        const f16* ksrc = Kh + ((size_t)bh * N_ + k0 + kvr) * DH + kvs;
        const f16* vsrc = Vt + ((size_t)bh * DH + kvr) * N_ + k0 + kvs;
        float4 ka0 = *(const float4*)(ksrc), ka1 = *(const float4*)(ksrc + 8);
        float4 va0 = *(const float4*)(vsrc), va1 = *(const float4*)(vsrc + 8);
        __syncthreads();
        *(float4*)&Ks[kvr * SP + kvs]     = ka0;
        *(float4*)&Ks[kvr * SP + kvs + 8] = ka1;
        *(float4*)&Vs[kvr * SP + kvs]     = va0;
        *(float4*)&Vs[kvr * SP + kvs + 8] = va1;
        __syncthreads();

        const u64 aw = arow[k0 >> 6];
        float rs = 0.f;

        // ---- S^T = K · Q^T, two 32-key tiles ----
#pragma unroll
        for (int m = 0; m < 2; m++) {
            floatx16 sacc = z16;
#pragma unroll
            for (int s = 0; s < 4; s++) {
                half8 a = *(const half8*)&Ks[(m * 32 + l31) * SP + s * 16 + hf * 8];
                sacc = __builtin_amdgcn_mfma_f32_32x32x16_f16(a, qf[s], sacc, 0, 0, 0);
            }
            // epilogue: reg -> key row = (reg&3) + 8*(reg>>2) + 4*hf
#pragma unroll
            for (int rg = 0; rg < 4; rg++) {
                const unsigned int nib =
                    (unsigned int)(aw >> (m * 32 + rg * 8 + hf * 4)) & 0xFu;
                half4v pv;
#pragma unroll
                for (int r = 0; r < 4; r++) {
                    float sv = fminf(fmaxf(sacc[rg * 4 + r], -CLIP), CLIP);
                    sv = ((nib >> r) & 1u) ? sv : -CLIP;
                    const float ev = __builtin_amdgcn_exp2f(sv);
                    rs += ev;
                    pv[r] = (f16)ev;
                }
                *(half4v*)&Ps[l31 * SP + m * 32 + rg * 8 + hf * 4] = pv;
            }
        }
        // full 64-key rowsum for this lane's q (other half covered by lane^32)
        rs += __shfl_xor(rs, 32);
        rs_ch += rs;

        // ---- ctx^T += V^T · P^T  (P wave-private; B[k=key][n=q]) ----
#pragma unroll
        for (int s = 0; s < 4; s++) {
            half8 pf = *(const half8*)&Ps[l31 * SP + s * 16 + hf * 8];
            half8 v0 = *(const half8*)&Vs[l31 * SP + s * 16 + hf * 8];
            half8 v1 = *(const half8*)&Vs[(32 + l31) * SP + s * 16 + hf * 8];
            ctx0 = __builtin_amdgcn_mfma_f32_32x32x16_f16(v0, pf, ctx0, 0, 0, 0);
            ctx1 = __builtin_amdgcn_mfma_f32_32x32x16_f16(v1, pf, ctx1, 0, 0, 0);
        }
    }

    // normalize + store: d = dt*32 + rg*8 + hf*4 + r  (4 contiguous f16 per rg)
    const float inv = 1.0f / rs_ch;
    f16* dst = CTXP + (((size_t)sp * B_ + b) * N_ + qglob) * F_ + h * DH;
#pragma unroll
    for (int rg = 0; rg < 4; rg++) {
        half4v h0, h1;
#pragma unroll
        for (int r = 0; r < 4; r++) {
            h0[r] = (f16)(ctx0[rg * 4 + r] * inv);
            h1[r] = (f16)(ctx1[rg * 4 + r] * inv);
        }
        *(half4v*)&dst[rg * 8 + hf * 4]      = h0;
        *(half4v*)&dst[32 + rg * 8 + hf * 4] = h1;
    }
}

// ---------------------------------------------------------------------------
// Kernel 3: fused [sum 8 partials] + [ctx @ Wo^T + bo + x] + LayerNorm.
// 32 rows per block; Wo staged once per f0-step, shared by both row-groups.
// ---------------------------------------------------------------------------
__global__ __launch_bounds__(256) void out_mfma(
    const f16* __restrict__ CTXP, const float* __restrict__ x,
    const f16* __restrict__ Woh, const float* __restrict__ bo,
    const float* __restrict__ gamma, const float* __restrict__ beta,
    float* __restrict__ out)
{
    const int n0 = blockIdx.x * 32;
    const int tid  = threadIdx.x;
    const int wave = tid >> 6, lane = tid & 63;
    const int quad = lane >> 4, l16 = lane & 15;
    const int wrow = tid >> 2, wseg = tid & 3;

    __shared__ f16 cs[32 * SPW];
    __shared__ f16 wtile[256 * SP];
    __shared__ float red0[4][32], red1[4][32];

    {   // stage ctx rows: sum 8 f16 split-partials in fp32, store f16
        const int row = tid >> 4, c0 = (tid & 15) * 16;
        const size_t S = (size_t)BN * F_;
#pragma unroll
        for (int g2 = 0; g2 < 2; g2++) {
            const int rr = g2 * 16 + row;
            const f16* p = CTXP + (size_t)(n0 + rr) * F_ + c0;
#pragma unroll
            for (int g = 0; g < 2; g++) {
                float v[8] = {0.f,0.f,0.f,0.f,0.f,0.f,0.f,0.f};
#pragma unroll
                for (int pp = 0; pp < 8; pp++) {
                    half8 s = *(const half8*)(p + (size_t)pp * S + g * 8);
#pragma unroll
                    for (int e = 0; e < 8; e++) v[e] += (float)s[e];
                }
                half8 o;
#pragma unroll
                for (int e = 0; e < 8; e++) o[e] = (f16)v[e];
                *(half8*)&cs[rr * SPW + c0 + g * 8] = o;
            }
        }
    }

    floatx4 zz = {0.f, 0.f, 0.f, 0.f};
    floatx4 acc[2][4] = {{zz, zz, zz, zz}, {zz, zz, zz, zz}};

#pragma unroll
    for (int f0 = 0; f0 < F_; f0 += 64) {
        __syncthreads();   // covers cs staging (iter 0) and prior frag reads
#pragma unroll
        for (int rr = 0; rr < 4; rr++) {
            const int o = rr * 64 + wrow;
            const f16* src = Woh + (size_t)o * F_ + f0 + wseg * 16;
            *(float4*)&wtile[o * SP + wseg * 16]     = *(const float4*)(src);
            *(float4*)&wtile[o * SP + wseg * 16 + 8] = *(const float4*)(src + 8);
        }
        __syncthreads();
        half8 a00 = *(const half8*)&cs[l16 * SPW + f0 + quad * 8];
        half8 a01 = *(const half8*)&cs[l16 * SPW + f0 + 32 + quad * 8];
        half8 a10 = *(const half8*)&cs[(16 + l16) * SPW + f0 + quad * 8];
        half8 a11 = *(const half8*)&cs[(16 + l16) * SPW + f0 + 32 + quad * 8];
#pragma unroll
        for (int ot = 0; ot < 4; ot++) {
            const int o = wave * 64 + ot * 16 + l16;
            half8 b0 = *(const half8*)&wtile[o * SP + quad * 8];
            half8 b1 = *(const half8*)&wtile[o * SP + 32 + quad * 8];
            acc[0][ot] = __builtin_amdgcn_mfma_f32_16x16x32_f16(a00, b0, acc[0][ot], 0, 0, 0);
            acc[0][ot] = __builtin_amdgcn_mfma_f32_16x16x32_f16(a01, b1, acc[0][ot], 0, 0, 0);
            acc[1][ot] = __builtin_amdgcn_mfma_f32_16x16x32_f16(a10, b0, acc[1][ot], 0, 0, 0);
            acc[1][ot] = __builtin_amdgcn_mfma_f32_16x16x32_f16(a11, b1, acc[1][ot], 0, 0, 0);
        }
    }

    // bias + residual
#pragma unroll
    for (int g2 = 0; g2 < 2; g2++)
#pragma unroll
        for (int ot = 0; ot < 4; ot++) {
            const int o = wave * 64 + ot * 16 + l16;
            const float bo_ = bo[o];
#pragma unroll
            for (int r = 0; r < 4; r++)
                acc[g2][ot][r] += bo_ + x[(size_t)(n0 + g2 * 16 + quad * 4 + r) * F_ + o];
        }

    // per-row partial sums over this wave's 64 cols
#pragma unroll
    for (int g2 = 0; g2 < 2; g2++)
#pragma unroll
        for (int r = 0; r < 4; r++) {
            float s = (acc[g2][0][r] + acc[g2][1][r]) + (acc[g2][2][r] + acc[g2][3][r]);
            float q = (acc[g2][0][r] * acc[g2][0][r] + acc[g2][1][r] * acc[g2][1][r]) +
                      (acc[g2][2][r] * acc[g2][2][r] + acc[g2][3][r] * acc[g2][3][r]);
            s += __shfl_xor(s, 1); q += __shfl_xor(q, 1);
            s += __shfl_xor(s, 2); q += __shfl_xor(q, 2);
            s += __shfl_xor(s, 4); q += __shfl_xor(q, 4);
            s += __shfl_xor(s, 8); q += __shfl_xor(q, 8);
            if (l16 == 0) {
                red0[wave][g2 * 16 + quad * 4 + r] = s;
                red1[wave][g2 * 16 + quad * 4 + r] = q;
            }
        }
    __syncthreads();

#pragma unroll
    for (int g2 = 0; g2 < 2; g2++)
#pragma unroll
        for (int r = 0; r < 4; r++) {
            const int rr = g2 * 16 + quad * 4 + r;
            const float S  = (red0[0][rr] + red0[1][rr]) + (red0[2][rr] + red0[3][rr]);
            const float Q2 = (red1[0][rr] + red1[1][rr]) + (red1[2][rr] + red1[3][rr]);
            const float mu  = S * (1.0f / F_);
            const float var = Q2 * (1.0f / F_) - mu * mu;
            const float inv = rsqrtf(var + 1e-5f);
#pragma unroll
            for (int ot = 0; ot < 4; ot++) {
                const int o = wave * 64 + ot * 16 + l16;
                out[(size_t)(n0 + rr) * F_ + o] =
                    (acc[g2][ot][r] - mu) * inv * gamma[o] + beta[o];
            }
        }
}

// ---------------------------------------------------------------------------
extern "C" void kernel_launch(void* const* d_in, const int* in_sizes, int n_in,
                              void* d_out, int out_size, void* d_ws, size_t ws_size,
                              hipStream_t stream)
{
    const float* x     = (const float*)d_in[0];
    const int*   adj   = (const int*)  d_in[1];
    const float* Wq    = (const float*)d_in[2];
    const float* bq    = (const float*)d_in[3];
    const float* Wk    = (const float*)d_in[4];
    const float* bk    = (const float*)d_in[5];
    const float* Wv    = (const float*)d_in[6];
    const float* bv    = (const float*)d_in[7];
    const float* Wo    = (const float*)d_in[8];
    const float* bo    = (const float*)d_in[9];
    const float* gamma = (const float*)d_in[10];
    const float* beta  = (const float*)d_in[11];
    float* out = (float*)d_out;

    float* ws = (float*)d_ws;
    f16*   CTXP = (f16*)(ws);                       // 16.8M halves (8,388,608 fl)
    f16*   Qh   = (f16*)(ws + 8388608);             // 2M halves
    f16*   Kh   = (f16*)(ws + 9437184);
    f16*   Vt   = (f16*)(ws + 10485760);
    u64*   Padj = (u64*)(ws + 11534336);            // 512 KB
    f16*   Woh  = (f16*)(ws + 11665408);            // 64K halves
    // Overlays inside the CTXP region: consumed by proj BEFORE attn writes CTXP.
    f16*   xh   = CTXP;                             // 2M halves
    f16*   Wqh  = (f16*)(ws + 1048576);
    f16*   Wkh  = (f16*)(ws + 1081344);
    f16*   Wvh  = (f16*)(ws + 1114112);

    hipLaunchKernelGGL(prep_kernel, dim3(18688), dim3(256), 0, stream,
                       adj, Padj, x, xh, Wq, Wqh, Wk, Wkh, Wv, Wvh, Wo, Woh);
    hipLaunchKernelGGL(proj_mfma, dim3(BN / 64, 2, 3), dim3(256), 0, stream,
                       xh, Wqh, Wkh, Wvh, bq, bk, bv, Qh, Kh, Vt);
    hipLaunchKernelGGL(attn_mfma, dim3(128, H_, B_), dim3(256), 0, stream,
                       Qh, Kh, Vt, Padj, CTXP);
    hipLaunchKernelGGL(out_mfma, dim3(BN / 32), dim3(256), 0, stream,
                       CTXP, x, Woh, bo, gamma, beta, out);
}